// Round 2
// baseline (2454.278 us; speedup 1.0000x reference)
//
#include <hip/hip_runtime.h>

#define NPTS 8192
#define NSAMP 1024
#define NBATCH 8
#define KNB 32

// Exact-match squared distance: ((dx*dx + dy*dy) + dz*dz) with no FMA contraction,
// matching XLA's f32 reduce over the last axis (left-assoc, separate mul/add).
__device__ __forceinline__ float sqdist_rn(float px, float py, float pz,
                                           float qx, float qy, float qz) {
  float dx = px - qx, dy = py - qy, dz = pz - qz;
  return __fadd_rn(__fadd_rn(__fmul_rn(dx, dx), __fmul_rn(dy, dy)), __fmul_rn(dz, dz));
}

// ---------------------------------------------------------------------------
// Kernel 1: farthest point sampling. One block per batch, 512 threads,
// 16 points/thread in registers. One barrier per step:
//  - per-thread update+argmax (lexicographic max on (d, -index))
//  - 6-round wave shuffle reduce
//  - in-wave winner lane writes (v,i,x,y,z) to double-buffered LDS slots
//  - barrier; all threads tree-reduce the 8 wave winners (coords carried along,
//    so no dependent indexed coord fetch on the critical path)
// ---------------------------------------------------------------------------
__global__ __launch_bounds__(512) void fps_kernel(const float* __restrict__ xyz,
                                                  float* __restrict__ out_newxyz) {
  __shared__ __align__(16) float red_v[2][8];
  __shared__ __align__(16) float red_x[2][8];
  __shared__ __align__(16) float red_y[2][8];
  __shared__ __align__(16) float red_z[2][8];
  __shared__ __align__(16) int red_i[2][8];
  __shared__ float p0[3];

  const int b = blockIdx.x;
  const int tid = threadIdx.x;
  const int lane = tid & 63;
  const int wv = tid >> 6;
  const float* xb = xyz + (size_t)b * 3 * NPTS;

  float X[16], Y[16], Z[16], Dm[16];
#pragma unroll
  for (int j = 0; j < 16; j++) {
    int n = tid + j * 512;
    X[j] = xb[n];
    Y[j] = xb[NPTS + n];
    Z[j] = xb[2 * NPTS + n];
    Dm[j] = 1e10f;
  }
  if (tid == 0) { p0[0] = X[0]; p0[1] = Y[0]; p0[2] = Z[0]; }
  __syncthreads();
  float sx = p0[0], sy = p0[1], sz = p0[2];  // selection 0 = point 0

  for (int t = 0; t < NSAMP; t++) {
    if (tid == 0) {
      out_newxyz[(b * 3 + 0) * NSAMP + t] = sx;
      out_newxyz[(b * 3 + 1) * NSAMP + t] = sy;
      out_newxyz[(b * 3 + 2) * NSAMP + t] = sz;
    }
    // distance update + per-thread argmax (ascending j => first-max tie-break,
    // and index order within a thread is ascending global index)
    float bv = -1.0f;
    int bi = NPTS;
#pragma unroll
    for (int j = 0; j < 16; j++) {
      float dd = sqdist_rn(X[j], Y[j], Z[j], sx, sy, sz);
      float dm = fminf(Dm[j], dd);
      Dm[j] = dm;
      if (dm > bv) { bv = dm; bi = tid + j * 512; }
    }
    // wave butterfly reduce, lexicographic max on (v, -i)
#pragma unroll
    for (int m = 1; m < 64; m <<= 1) {
      float ov = __shfl_xor(bv, m, 64);
      int oi = __shfl_xor(bi, m, 64);
      bool take = (ov > bv) || (ov == bv && oi < bi);
      bv = take ? ov : bv;
      bi = take ? oi : bi;
    }
    // winner lane of this wave publishes (v,i,x,y,z); its registers hold the point
    const int par = t & 1;
    if (lane == (bi & 63)) {
      int jj = bi >> 9;
      float vx = 0.f, vy = 0.f, vz = 0.f;
#pragma unroll
      for (int j = 0; j < 16; j++)
        if (j == jj) { vx = X[j]; vy = Y[j]; vz = Z[j]; }
      red_v[par][wv] = bv;
      red_i[par][wv] = bi;
      red_x[par][wv] = vx;
      red_y[par][wv] = vy;
      red_z[par][wv] = vz;
    }
    __syncthreads();
    // all threads redundantly tree-reduce the 8 wave winners (broadcast b128 reads)
    float cv[8], cx[8], cy[8], cz[8];
    int ci[8];
    *(float4*)&cv[0] = *(const float4*)&red_v[par][0];
    *(float4*)&cv[4] = *(const float4*)&red_v[par][4];
    *(float4*)&cx[0] = *(const float4*)&red_x[par][0];
    *(float4*)&cx[4] = *(const float4*)&red_x[par][4];
    *(float4*)&cy[0] = *(const float4*)&red_y[par][0];
    *(float4*)&cy[4] = *(const float4*)&red_y[par][4];
    *(float4*)&cz[0] = *(const float4*)&red_z[par][0];
    *(float4*)&cz[4] = *(const float4*)&red_z[par][4];
    *(int4*)&ci[0] = *(const int4*)&red_i[par][0];
    *(int4*)&ci[4] = *(const int4*)&red_i[par][4];
#pragma unroll
    for (int off = 4; off >= 1; off >>= 1) {
#pragma unroll
      for (int k = 0; k < 8; k++) {
        if (k < off) {
          bool take = (cv[k + off] > cv[k]) ||
                      (cv[k + off] == cv[k] && ci[k + off] < ci[k]);
          if (take) {
            cv[k] = cv[k + off]; ci[k] = ci[k + off];
            cx[k] = cx[k + off]; cy[k] = cy[k + off]; cz[k] = cz[k + off];
          }
        }
      }
    }
    sx = cx[0]; sy = cy[0]; sz = cz[0];
  }
}

// ---------------------------------------------------------------------------
// Kernel 2: ball query + attention mean. One wave per (b,s). Scans points in
// ascending index order in chunks of 64, collects the first K in-radius
// indices (ballot + prefix popcount), pads with the first hit.
// ---------------------------------------------------------------------------
__global__ __launch_bounds__(256) void ballq_kernel(const float* __restrict__ xyz,
                                                    const float* __restrict__ att,
                                                    const float* __restrict__ newxyz,
                                                    int* __restrict__ idx_out,
                                                    float* __restrict__ att_out) {
  __shared__ int rowbuf[4][KNB];
  const int wv = threadIdx.x >> 6;
  const int lane = threadIdx.x & 63;
  const int g = blockIdx.x * 4 + wv;  // b*NSAMP + s
  const int b = g >> 10;
  const int s = g & 1023;
  const float* xb = xyz + (size_t)b * 3 * NPTS;

  float qx = newxyz[(b * 3 + 0) * NSAMP + s];
  float qy = newxyz[(b * 3 + 1) * NSAMP + s];
  float qz = newxyz[(b * 3 + 2) * NSAMP + s];

  int have = 0;
  int firstn = 0;
  for (int c = 0; c < NPTS / 64; c++) {
    int n = c * 64 + lane;
    float dd = sqdist_rn(xb[n], xb[NPTS + n], xb[2 * NPTS + n], qx, qy, qz);
    bool inb = (dd <= 0.04f);
    unsigned long long m = __ballot(inb);
    if (have == 0 && m != 0ull) firstn = c * 64 + __builtin_ctzll(m);
    int pre = __popcll(m & ((1ull << lane) - 1ull));
    if (inb && (have + pre) < KNB) rowbuf[wv][have + pre] = n;
    have += __popcll(m);
    if (have >= KNB) break;
  }
  if (have > KNB) have = KNB;
  if (lane < KNB && lane >= have) rowbuf[wv][lane] = firstn;  // pad

  float av = 0.0f;
  if (lane < KNB) {
    int myidx = rowbuf[wv][lane];
    idx_out[(size_t)g * KNB + lane] = myidx;
    av = att[(size_t)b * NPTS + myidx];
  }
#pragma unroll
  for (int m = 1; m < 64; m <<= 1) av += __shfl_xor(av, m, 64);
  if (lane == 0) att_out[g] = av * 0.03125f;  // mean over K=32 (exact /32)
}

// ---------------------------------------------------------------------------
// Kernel 3: gather features + 3-layer MLP + max over K. One 256-thread block
// per (b,s). feat [67][32] and h [64][36] (padded stride) in LDS; weights
// streamed from global (L1/L2 broadcast). f32 fmaf throughout.
// ---------------------------------------------------------------------------
__global__ __launch_bounds__(256) void mlp_kernel(
    const float* __restrict__ xyz, const float* __restrict__ pts,
    const float* __restrict__ newxyz, const int* __restrict__ idx,
    const float* __restrict__ w0, const float* __restrict__ b0,
    const float* __restrict__ w1, const float* __restrict__ b1,
    const float* __restrict__ w2, const float* __restrict__ b2,
    float* __restrict__ out_np) {
  const int g = blockIdx.x;
  const int b = g >> 10;
  const int s = g & 1023;
  const int t = threadIdx.x;

  __shared__ __align__(16) float feat[67 * 32];
  __shared__ __align__(16) float h0s[64 * 36];
  __shared__ __align__(16) float h1s[64 * 36];
  __shared__ int sidx[KNB];

  if (t < KNB) sidx[t] = idx[(size_t)g * KNB + t];
  __syncthreads();

  // gather: rows 0..2 = g_norm (xyz - query), rows 3..66 = point features
  {
    int k = t & 31, rg = t >> 5;
    int n = sidx[k];
    const float* pb = pts + (size_t)b * 64 * NPTS;
    for (int r = rg; r < 67; r += 8) {
      float v;
      if (r < 3)
        v = xyz[((size_t)b * 3 + r) * NPTS + n] - newxyz[(b * 3 + r) * NSAMP + s];
      else
        v = pb[(size_t)(r - 3) * NPTS + n];
      feat[r * 32 + k] = v;
    }
  }
  __syncthreads();

  const int kq = t & 7;   // k block = 4*kq .. +4
  const int og = t >> 3;  // o = 2*og, 2*og+1

  // ---- layer 0: 67 -> 64 ----
  {
    float a0[8];
    float bu = b0[2 * og], bw = b0[2 * og + 1];
    a0[0] = a0[1] = a0[2] = a0[3] = bu;
    a0[4] = a0[5] = a0[6] = a0[7] = bw;
    const float* wr0 = w0 + (2 * og) * 67;
    const float* wr1 = wr0 + 67;
    for (int c = 0; c < 67; c++) {
      float4 f = *(const float4*)&feat[c * 32 + kq * 4];
      float u = wr0[c], v = wr1[c];
      a0[0] = fmaf(u, f.x, a0[0]); a0[1] = fmaf(u, f.y, a0[1]);
      a0[2] = fmaf(u, f.z, a0[2]); a0[3] = fmaf(u, f.w, a0[3]);
      a0[4] = fmaf(v, f.x, a0[4]); a0[5] = fmaf(v, f.y, a0[5]);
      a0[6] = fmaf(v, f.z, a0[6]); a0[7] = fmaf(v, f.w, a0[7]);
    }
    float4 r0, r1;
    r0.x = fmaxf(a0[0], 0.f); r0.y = fmaxf(a0[1], 0.f);
    r0.z = fmaxf(a0[2], 0.f); r0.w = fmaxf(a0[3], 0.f);
    r1.x = fmaxf(a0[4], 0.f); r1.y = fmaxf(a0[5], 0.f);
    r1.z = fmaxf(a0[6], 0.f); r1.w = fmaxf(a0[7], 0.f);
    *(float4*)&h0s[(2 * og) * 36 + kq * 4] = r0;
    *(float4*)&h0s[(2 * og + 1) * 36 + kq * 4] = r1;
  }
  __syncthreads();

  // ---- layer 1: 64 -> 64 ----
  {
    float a1[8];
    float bu = b1[2 * og], bw = b1[2 * og + 1];
    a1[0] = a1[1] = a1[2] = a1[3] = bu;
    a1[4] = a1[5] = a1[6] = a1[7] = bw;
    const float* wr0 = w1 + (2 * og) * 64;
    const float* wr1 = wr0 + 64;
    for (int c = 0; c < 64; c++) {
      float4 f = *(const float4*)&h0s[c * 36 + kq * 4];
      float u = wr0[c], v = wr1[c];
      a1[0] = fmaf(u, f.x, a1[0]); a1[1] = fmaf(u, f.y, a1[1]);
      a1[2] = fmaf(u, f.z, a1[2]); a1[3] = fmaf(u, f.w, a1[3]);
      a1[4] = fmaf(v, f.x, a1[4]); a1[5] = fmaf(v, f.y, a1[5]);
      a1[6] = fmaf(v, f.z, a1[6]); a1[7] = fmaf(v, f.w, a1[7]);
    }
    float4 r0, r1;
    r0.x = fmaxf(a1[0], 0.f); r0.y = fmaxf(a1[1], 0.f);
    r0.z = fmaxf(a1[2], 0.f); r0.w = fmaxf(a1[3], 0.f);
    r1.x = fmaxf(a1[4], 0.f); r1.y = fmaxf(a1[5], 0.f);
    r1.z = fmaxf(a1[6], 0.f); r1.w = fmaxf(a1[7], 0.f);
    *(float4*)&h1s[(2 * og) * 36 + kq * 4] = r0;
    *(float4*)&h1s[(2 * og + 1) * 36 + kq * 4] = r1;
  }
  __syncthreads();

  // ---- layer 2: 64 -> 128, then max over k ----
  {
    const int kq2 = t & 3;   // k block = 8*kq2 .. +8
    const int og2 = t >> 2;  // o = 2*og2, 2*og2+1
    float a2[16];
    float bu = b2[2 * og2], bw = b2[2 * og2 + 1];
#pragma unroll
    for (int i = 0; i < 8; i++) { a2[i] = bu; a2[8 + i] = bw; }
    const float* wr0 = w2 + (2 * og2) * 64;
    const float* wr1 = wr0 + 64;
    for (int c = 0; c < 64; c++) {
      float4 fA = *(const float4*)&h1s[c * 36 + kq2 * 8];
      float4 fB = *(const float4*)&h1s[c * 36 + kq2 * 8 + 4];
      float u = wr0[c], v = wr1[c];
      a2[0] = fmaf(u, fA.x, a2[0]);  a2[1] = fmaf(u, fA.y, a2[1]);
      a2[2] = fmaf(u, fA.z, a2[2]);  a2[3] = fmaf(u, fA.w, a2[3]);
      a2[4] = fmaf(u, fB.x, a2[4]);  a2[5] = fmaf(u, fB.y, a2[5]);
      a2[6] = fmaf(u, fB.z, a2[6]);  a2[7] = fmaf(u, fB.w, a2[7]);
      a2[8] = fmaf(v, fA.x, a2[8]);  a2[9] = fmaf(v, fA.y, a2[9]);
      a2[10] = fmaf(v, fA.z, a2[10]); a2[11] = fmaf(v, fA.w, a2[11]);
      a2[12] = fmaf(v, fB.x, a2[12]); a2[13] = fmaf(v, fB.y, a2[13]);
      a2[14] = fmaf(v, fB.z, a2[14]); a2[15] = fmaf(v, fB.w, a2[15]);
    }
    // relu then max over k == max then relu (relu is monotone)
    float m0 = a2[0], m1 = a2[8];
#pragma unroll
    for (int i = 1; i < 8; i++) { m0 = fmaxf(m0, a2[i]); m1 = fmaxf(m1, a2[8 + i]); }
    m0 = fmaxf(m0, 0.f);
    m1 = fmaxf(m1, 0.f);
    // reduce over the 4 lanes sharing og2 (kq2 = 0..3, adjacent lanes)
    m0 = fmaxf(m0, __shfl_xor(m0, 1, 64));
    m0 = fmaxf(m0, __shfl_xor(m0, 2, 64));
    m1 = fmaxf(m1, __shfl_xor(m1, 1, 64));
    m1 = fmaxf(m1, __shfl_xor(m1, 2, 64));
    if (kq2 == 0) {
      out_np[((size_t)b * 128 + 2 * og2) * NSAMP + s] = m0;
      out_np[((size_t)b * 128 + 2 * og2 + 1) * NSAMP + s] = m1;
    }
  }
}

extern "C" void kernel_launch(void* const* d_in, const int* in_sizes, int n_in,
                              void* d_out, int out_size, void* d_ws, size_t ws_size,
                              hipStream_t stream) {
  (void)in_sizes; (void)n_in; (void)out_size; (void)ws_size;
  const float* xyz = (const float*)d_in[0];
  const float* pts = (const float*)d_in[1];
  const float* att = (const float*)d_in[2];
  const float* w0 = (const float*)d_in[3];
  const float* b0 = (const float*)d_in[4];
  const float* w1 = (const float*)d_in[5];
  const float* b1 = (const float*)d_in[6];
  const float* w2 = (const float*)d_in[7];
  const float* b2 = (const float*)d_in[8];

  float* out = (float*)d_out;
  float* out_newxyz = out;                                     // (B,3,S)
  float* out_newpts = out + NBATCH * 3 * NSAMP;                // (B,128,S)
  float* out_att = out + NBATCH * 3 * NSAMP + NBATCH * 128 * NSAMP;  // (B,1,S)
  int* idx_ws = (int*)d_ws;  // (B*S, K) int32 = 1 MB

  fps_kernel<<<NBATCH, 512, 0, stream>>>(xyz, out_newxyz);
  ballq_kernel<<<(NBATCH * NSAMP) / 4, 256, 0, stream>>>(xyz, att, out_newxyz, idx_ws, out_att);
  mlp_kernel<<<NBATCH * NSAMP, 256, 0, stream>>>(xyz, pts, out_newxyz, idx_ws,
                                                 w0, b0, w1, b1, w2, b2, out_newpts);
}

// Round 3
// 1271.132 us; speedup vs baseline: 1.9308x; 1.9308x over previous
//
#include <hip/hip_runtime.h>

#define NPTS 8192
#define NSAMP 1024
#define NBATCH 8
#define KNB 32

typedef float f32x2 __attribute__((ext_vector_type(2)));

// Packed f32 ops — IEEE rn per half, identical results to scalar v_add/v_mul.
__device__ __forceinline__ f32x2 pk_add(f32x2 a, f32x2 b) {
  f32x2 d; asm("v_pk_add_f32 %0, %1, %2" : "=v"(d) : "v"(a), "v"(b)); return d;
}
__device__ __forceinline__ f32x2 pk_mul(f32x2 a, f32x2 b) {
  f32x2 d; asm("v_pk_mul_f32 %0, %1, %2" : "=v"(d) : "v"(a), "v"(b)); return d;
}

// One DPP min-round on a u64 key (lo/hi halves moved separately, 64-bit compare).
// old = own value, so lanes with invalid source keep their value (harmless for min).
#define DPP_MIN_ROUND(k, CTRL)                                                         \
  do {                                                                                 \
    unsigned _lo = (unsigned)(k), _hi = (unsigned)((k) >> 32);                         \
    unsigned _plo = (unsigned)__builtin_amdgcn_update_dpp((int)_lo, (int)_lo, CTRL,    \
                                                          0xF, 0xF, false);            \
    unsigned _phi = (unsigned)__builtin_amdgcn_update_dpp((int)_hi, (int)_hi, CTRL,    \
                                                          0xF, 0xF, false);            \
    unsigned long long _ok = (((unsigned long long)_phi) << 32) | _plo;                \
    if (_ok < (k)) (k) = _ok;                                                          \
  } while (0)

// Exact-match squared distance for ballq: ((dx*dx + dy*dy) + dz*dz), rn ops, no FMA.
__device__ __forceinline__ float sqdist_rn(float px, float py, float pz,
                                           float qx, float qy, float qz) {
  float dx = px - qx, dy = py - qy, dz = pz - qz;
  return __fadd_rn(__fadd_rn(__fmul_rn(dx, dx), __fmul_rn(dy, dy)), __fmul_rn(dz, dz));
}

// ---------------------------------------------------------------------------
// Kernel 1: farthest point sampling. One block per batch, 512 threads, 16
// points/thread (8 f32x2 pairs) in registers. Per step:
//   update (packed math) -> per-thread argmax -> u64 key (~bits(d)<<32 | n)
//   6 DPP rounds wave min-reduce -> lane63 writes 8B to LDS -> ONE barrier
//   read wkeys[lane&7] + 3 DPP rounds -> global winner in every lane
//   coords re-fetched uniformly from global (L2). No stores in the loop.
// Exact semantics: min over keys == argmax by (dist desc, index asc) ==
// jnp.argmax first-occurrence; p + (-q) == p - q bitwise.
// ---------------------------------------------------------------------------
__global__ __launch_bounds__(512) void fps_kernel(const float* __restrict__ xyz,
                                                  float* __restrict__ out_newxyz) {
  __shared__ unsigned long long wkeys[2][8];

  const int b = blockIdx.x;
  const int tid = threadIdx.x;
  const int lane = tid & 63;
  const int wv = tid >> 6;
  const float* xb = xyz + (size_t)b * 3 * NPTS;

  f32x2 X2[8], Y2[8], Z2[8], D2[8];
#pragma unroll
  for (int j = 0; j < 8; j++) {
    int n0 = tid + (2 * j) * 512, n1 = tid + (2 * j + 1) * 512;
    X2[j].x = xb[n0];            X2[j].y = xb[n1];
    Y2[j].x = xb[NPTS + n0];     Y2[j].y = xb[NPTS + n1];
    Z2[j].x = xb[2 * NPTS + n0]; Z2[j].y = xb[2 * NPTS + n1];
    D2[j].x = 1e10f;             D2[j].y = 1e10f;
  }
  // selection 0 = point 0 (uniform read)
  float sx = xb[0], sy = xb[NPTS], sz = xb[2 * NPTS];
  float c0x = 0.f, c0y = 0.f, c0z = 0.f, c1x = 0.f, c1y = 0.f, c1z = 0.f;

  for (int t = 0; t < NSAMP; t++) {
    // stash current selection's coords in the owning thread's registers
    if (t == tid) { c0x = sx; c0y = sy; c0z = sz; }
    if (t == tid + 512) { c1x = sx; c1y = sy; c1z = sz; }

    f32x2 nqx, nqy, nqz;
    nqx.x = -sx; nqx.y = -sx;
    nqy.x = -sy; nqy.y = -sy;
    nqz.x = -sz; nqz.y = -sz;

    float bv = -1.0f;
    int bj = 0;
#pragma unroll
    for (int j = 0; j < 8; j++) {
      f32x2 dx = pk_add(X2[j], nqx);
      f32x2 dy = pk_add(Y2[j], nqy);
      f32x2 dz = pk_add(Z2[j], nqz);
      f32x2 dd = pk_add(pk_add(pk_mul(dx, dx), pk_mul(dy, dy)), pk_mul(dz, dz));
      float m0 = fminf(D2[j].x, dd.x);
      float m1 = fminf(D2[j].y, dd.y);
      D2[j].x = m0;
      D2[j].y = m1;
      // ascending global index order (x before y, j ascending); strict > keeps first
      if (m0 > bv) { bv = m0; bj = 2 * j; }
      if (m1 > bv) { bv = m1; bj = 2 * j + 1; }
    }
    unsigned n = (unsigned)tid + (unsigned)bj * 512u;
    unsigned long long key =
        (((unsigned long long)(~__float_as_uint(bv))) << 32) | (unsigned long long)n;

    // wave64 min-reduce: row_shr 1/2/4/8, bcast15, bcast31 -> lane63 has wave min
    DPP_MIN_ROUND(key, 0x111);
    DPP_MIN_ROUND(key, 0x112);
    DPP_MIN_ROUND(key, 0x114);
    DPP_MIN_ROUND(key, 0x118);
    DPP_MIN_ROUND(key, 0x142);
    DPP_MIN_ROUND(key, 0x143);

    const int par = t & 1;
    if (lane == 63) wkeys[par][wv] = key;
    __syncthreads();

    // all lanes: read the 8 wave winners (8 banks, broadcast), 3-round group-of-8 min
    unsigned long long k8 = wkeys[par][lane & 7];
    DPP_MIN_ROUND(k8, 0xB1);   // quad_perm [1,0,3,2]  (^1)
    DPP_MIN_ROUND(k8, 0x4E);   // quad_perm [2,3,0,1]  (^2)
    DPP_MIN_ROUND(k8, 0x141);  // row_half_mirror      (i <-> 7-i)
    unsigned wid = (unsigned)__builtin_amdgcn_readfirstlane((int)(unsigned)k8);

    sx = xb[wid];
    sy = xb[NPTS + wid];
    sz = xb[2 * NPTS + wid];
  }

  out_newxyz[(b * 3 + 0) * NSAMP + tid] = c0x;
  out_newxyz[(b * 3 + 1) * NSAMP + tid] = c0y;
  out_newxyz[(b * 3 + 2) * NSAMP + tid] = c0z;
  out_newxyz[(b * 3 + 0) * NSAMP + 512 + tid] = c1x;
  out_newxyz[(b * 3 + 1) * NSAMP + 512 + tid] = c1y;
  out_newxyz[(b * 3 + 2) * NSAMP + 512 + tid] = c1z;
}

// ---------------------------------------------------------------------------
// Kernel 2: ball query + attention mean. One wave per (b,s). Scans points in
// ascending index order in chunks of 64, collects the first K in-radius
// indices (ballot + prefix popcount), pads with the first hit.
// ---------------------------------------------------------------------------
__global__ __launch_bounds__(256) void ballq_kernel(const float* __restrict__ xyz,
                                                    const float* __restrict__ att,
                                                    const float* __restrict__ newxyz,
                                                    int* __restrict__ idx_out,
                                                    float* __restrict__ att_out) {
  __shared__ int rowbuf[4][KNB];
  const int wv = threadIdx.x >> 6;
  const int lane = threadIdx.x & 63;
  const int g = blockIdx.x * 4 + wv;  // b*NSAMP + s
  const int b = g >> 10;
  const int s = g & 1023;
  const float* xb = xyz + (size_t)b * 3 * NPTS;

  float qx = newxyz[(b * 3 + 0) * NSAMP + s];
  float qy = newxyz[(b * 3 + 1) * NSAMP + s];
  float qz = newxyz[(b * 3 + 2) * NSAMP + s];

  int have = 0;
  int firstn = 0;
  for (int c = 0; c < NPTS / 64; c++) {
    int n = c * 64 + lane;
    float dd = sqdist_rn(xb[n], xb[NPTS + n], xb[2 * NPTS + n], qx, qy, qz);
    bool inb = (dd <= 0.04f);
    unsigned long long m = __ballot(inb);
    if (have == 0 && m != 0ull) firstn = c * 64 + __builtin_ctzll(m);
    int pre = __popcll(m & ((1ull << lane) - 1ull));
    if (inb && (have + pre) < KNB) rowbuf[wv][have + pre] = n;
    have += __popcll(m);
    if (have >= KNB) break;
  }
  if (have > KNB) have = KNB;
  if (lane < KNB && lane >= have) rowbuf[wv][lane] = firstn;  // pad

  float av = 0.0f;
  if (lane < KNB) {
    int myidx = rowbuf[wv][lane];
    idx_out[(size_t)g * KNB + lane] = myidx;
    av = att[(size_t)b * NPTS + myidx];
  }
#pragma unroll
  for (int m = 1; m < 64; m <<= 1) av += __shfl_xor(av, m, 64);
  if (lane == 0) att_out[g] = av * 0.03125f;  // mean over K=32 (exact /32)
}

// ---------------------------------------------------------------------------
// Kernel 3: gather features + 3-layer MLP + max over K. One 256-thread block
// per (b,s). feat [67][32] and h [64][36] (padded stride) in LDS; weights
// streamed from global (L1/L2 broadcast). f32 fmaf throughout.
// ---------------------------------------------------------------------------
__global__ __launch_bounds__(256) void mlp_kernel(
    const float* __restrict__ xyz, const float* __restrict__ pts,
    const float* __restrict__ newxyz, const int* __restrict__ idx,
    const float* __restrict__ w0, const float* __restrict__ b0,
    const float* __restrict__ w1, const float* __restrict__ b1,
    const float* __restrict__ w2, const float* __restrict__ b2,
    float* __restrict__ out_np) {
  const int g = blockIdx.x;
  const int b = g >> 10;
  const int s = g & 1023;
  const int t = threadIdx.x;

  __shared__ __align__(16) float feat[67 * 32];
  __shared__ __align__(16) float h0s[64 * 36];
  __shared__ __align__(16) float h1s[64 * 36];
  __shared__ int sidx[KNB];

  if (t < KNB) sidx[t] = idx[(size_t)g * KNB + t];
  __syncthreads();

  // gather: rows 0..2 = g_norm (xyz - query), rows 3..66 = point features
  {
    int k = t & 31, rg = t >> 5;
    int n = sidx[k];
    const float* pb = pts + (size_t)b * 64 * NPTS;
    for (int r = rg; r < 67; r += 8) {
      float v;
      if (r < 3)
        v = xyz[((size_t)b * 3 + r) * NPTS + n] - newxyz[(b * 3 + r) * NSAMP + s];
      else
        v = pb[(size_t)(r - 3) * NPTS + n];
      feat[r * 32 + k] = v;
    }
  }
  __syncthreads();

  const int kq = t & 7;   // k block = 4*kq .. +4
  const int og = t >> 3;  // o = 2*og, 2*og+1

  // ---- layer 0: 67 -> 64 ----
  {
    float a0[8];
    float bu = b0[2 * og], bw = b0[2 * og + 1];
    a0[0] = a0[1] = a0[2] = a0[3] = bu;
    a0[4] = a0[5] = a0[6] = a0[7] = bw;
    const float* wr0 = w0 + (2 * og) * 67;
    const float* wr1 = wr0 + 67;
    for (int c = 0; c < 67; c++) {
      float4 f = *(const float4*)&feat[c * 32 + kq * 4];
      float u = wr0[c], v = wr1[c];
      a0[0] = fmaf(u, f.x, a0[0]); a0[1] = fmaf(u, f.y, a0[1]);
      a0[2] = fmaf(u, f.z, a0[2]); a0[3] = fmaf(u, f.w, a0[3]);
      a0[4] = fmaf(v, f.x, a0[4]); a0[5] = fmaf(v, f.y, a0[5]);
      a0[6] = fmaf(v, f.z, a0[6]); a0[7] = fmaf(v, f.w, a0[7]);
    }
    float4 r0, r1;
    r0.x = fmaxf(a0[0], 0.f); r0.y = fmaxf(a0[1], 0.f);
    r0.z = fmaxf(a0[2], 0.f); r0.w = fmaxf(a0[3], 0.f);
    r1.x = fmaxf(a0[4], 0.f); r1.y = fmaxf(a0[5], 0.f);
    r1.z = fmaxf(a0[6], 0.f); r1.w = fmaxf(a0[7], 0.f);
    *(float4*)&h0s[(2 * og) * 36 + kq * 4] = r0;
    *(float4*)&h0s[(2 * og + 1) * 36 + kq * 4] = r1;
  }
  __syncthreads();

  // ---- layer 1: 64 -> 64 ----
  {
    float a1[8];
    float bu = b1[2 * og], bw = b1[2 * og + 1];
    a1[0] = a1[1] = a1[2] = a1[3] = bu;
    a1[4] = a1[5] = a1[6] = a1[7] = bw;
    const float* wr0 = w1 + (2 * og) * 64;
    const float* wr1 = wr0 + 64;
    for (int c = 0; c < 64; c++) {
      float4 f = *(const float4*)&h0s[c * 36 + kq * 4];
      float u = wr0[c], v = wr1[c];
      a1[0] = fmaf(u, f.x, a1[0]); a1[1] = fmaf(u, f.y, a1[1]);
      a1[2] = fmaf(u, f.z, a1[2]); a1[3] = fmaf(u, f.w, a1[3]);
      a1[4] = fmaf(v, f.x, a1[4]); a1[5] = fmaf(v, f.y, a1[5]);
      a1[6] = fmaf(v, f.z, a1[6]); a1[7] = fmaf(v, f.w, a1[7]);
    }
    float4 r0, r1;
    r0.x = fmaxf(a1[0], 0.f); r0.y = fmaxf(a1[1], 0.f);
    r0.z = fmaxf(a1[2], 0.f); r0.w = fmaxf(a1[3], 0.f);
    r1.x = fmaxf(a1[4], 0.f); r1.y = fmaxf(a1[5], 0.f);
    r1.z = fmaxf(a1[6], 0.f); r1.w = fmaxf(a1[7], 0.f);
    *(float4*)&h1s[(2 * og) * 36 + kq * 4] = r0;
    *(float4*)&h1s[(2 * og + 1) * 36 + kq * 4] = r1;
  }
  __syncthreads();

  // ---- layer 2: 64 -> 128, then max over k ----
  {
    const int kq2 = t & 3;   // k block = 8*kq2 .. +8
    const int og2 = t >> 2;  // o = 2*og2, 2*og2+1
    float a2[16];
    float bu = b2[2 * og2], bw = b2[2 * og2 + 1];
#pragma unroll
    for (int i = 0; i < 8; i++) { a2[i] = bu; a2[8 + i] = bw; }
    const float* wr0 = w2 + (2 * og2) * 64;
    const float* wr1 = wr0 + 64;
    for (int c = 0; c < 64; c++) {
      float4 fA = *(const float4*)&h1s[c * 36 + kq2 * 8];
      float4 fB = *(const float4*)&h1s[c * 36 + kq2 * 8 + 4];
      float u = wr0[c], v = wr1[c];
      a2[0] = fmaf(u, fA.x, a2[0]);  a2[1] = fmaf(u, fA.y, a2[1]);
      a2[2] = fmaf(u, fA.z, a2[2]);  a2[3] = fmaf(u, fA.w, a2[3]);
      a2[4] = fmaf(u, fB.x, a2[4]);  a2[5] = fmaf(u, fB.y, a2[5]);
      a2[6] = fmaf(u, fB.z, a2[6]);  a2[7] = fmaf(u, fB.w, a2[7]);
      a2[8] = fmaf(v, fA.x, a2[8]);  a2[9] = fmaf(v, fA.y, a2[9]);
      a2[10] = fmaf(v, fA.z, a2[10]); a2[11] = fmaf(v, fA.w, a2[11]);
      a2[12] = fmaf(v, fB.x, a2[12]); a2[13] = fmaf(v, fB.y, a2[13]);
      a2[14] = fmaf(v, fB.z, a2[14]); a2[15] = fmaf(v, fB.w, a2[15]);
    }
    // relu then max over k == max then relu (relu is monotone)
    float m0 = a2[0], m1 = a2[8];
#pragma unroll
    for (int i = 1; i < 8; i++) { m0 = fmaxf(m0, a2[i]); m1 = fmaxf(m1, a2[8 + i]); }
    m0 = fmaxf(m0, 0.f);
    m1 = fmaxf(m1, 0.f);
    // reduce over the 4 lanes sharing og2 (kq2 = 0..3, adjacent lanes)
    m0 = fmaxf(m0, __shfl_xor(m0, 1, 64));
    m0 = fmaxf(m0, __shfl_xor(m0, 2, 64));
    m1 = fmaxf(m1, __shfl_xor(m1, 1, 64));
    m1 = fmaxf(m1, __shfl_xor(m1, 2, 64));
    if (kq2 == 0) {
      out_np[((size_t)b * 128 + 2 * og2) * NSAMP + s] = m0;
      out_np[((size_t)b * 128 + 2 * og2 + 1) * NSAMP + s] = m1;
    }
  }
}

extern "C" void kernel_launch(void* const* d_in, const int* in_sizes, int n_in,
                              void* d_out, int out_size, void* d_ws, size_t ws_size,
                              hipStream_t stream) {
  (void)in_sizes; (void)n_in; (void)out_size; (void)ws_size;
  const float* xyz = (const float*)d_in[0];
  const float* pts = (const float*)d_in[1];
  const float* att = (const float*)d_in[2];
  const float* w0 = (const float*)d_in[3];
  const float* b0 = (const float*)d_in[4];
  const float* w1 = (const float*)d_in[5];
  const float* b1 = (const float*)d_in[6];
  const float* w2 = (const float*)d_in[7];
  const float* b2 = (const float*)d_in[8];

  float* out = (float*)d_out;
  float* out_newxyz = out;                                     // (B,3,S)
  float* out_newpts = out + NBATCH * 3 * NSAMP;                // (B,128,S)
  float* out_att = out + NBATCH * 3 * NSAMP + NBATCH * 128 * NSAMP;  // (B,1,S)
  int* idx_ws = (int*)d_ws;  // (B*S, K) int32 = 1 MB

  fps_kernel<<<NBATCH, 512, 0, stream>>>(xyz, out_newxyz);
  ballq_kernel<<<(NBATCH * NSAMP) / 4, 256, 0, stream>>>(xyz, att, out_newxyz, idx_ws, out_att);
  mlp_kernel<<<NBATCH * NSAMP, 256, 0, stream>>>(xyz, pts, out_newxyz, idx_ws,
                                                 w0, b0, w1, b1, w2, b2, out_newpts);
}

// Round 4
// 1225.510 us; speedup vs baseline: 2.0027x; 1.0372x over previous
//
#include <hip/hip_runtime.h>

#define NPTS 8192
#define NSAMP 1024
#define NBATCH 8
#define KNB 32

typedef float f32x2 __attribute__((ext_vector_type(2)));

// Packed f32 ops — IEEE rn per half, identical results to scalar v_add/v_mul.
__device__ __forceinline__ f32x2 pk_add(f32x2 a, f32x2 b) {
  f32x2 d; asm("v_pk_add_f32 %0, %1, %2" : "=v"(d) : "v"(a), "v"(b)); return d;
}
__device__ __forceinline__ f32x2 pk_mul(f32x2 a, f32x2 b) {
  f32x2 d; asm("v_pk_mul_f32 %0, %1, %2" : "=v"(d) : "v"(a), "v"(b)); return d;
}

// Single-dep-chain DPP reduce rounds (old = own value, safe for min/max).
#define DPP_FMAX_ROUND(v, CTRL)                                                        \
  do {                                                                                 \
    int _b = __float_as_int(v);                                                        \
    int _p = __builtin_amdgcn_update_dpp(_b, _b, CTRL, 0xF, 0xF, false);               \
    (v) = fmaxf((v), __int_as_float(_p));                                              \
  } while (0)

#define DPP_UMIN_ROUND(v, CTRL)                                                        \
  do {                                                                                 \
    unsigned _p = (unsigned)__builtin_amdgcn_update_dpp((int)(v), (int)(v), CTRL,      \
                                                        0xF, 0xF, false);              \
    if (_p < (v)) (v) = _p;                                                            \
  } while (0)

// u64 key min round (5 instrs) — only used for the 3 cross-wave rounds.
#define DPP_MIN_ROUND(k, CTRL)                                                         \
  do {                                                                                 \
    unsigned _lo = (unsigned)(k), _hi = (unsigned)((k) >> 32);                         \
    unsigned _plo = (unsigned)__builtin_amdgcn_update_dpp((int)_lo, (int)_lo, CTRL,    \
                                                          0xF, 0xF, false);            \
    unsigned _phi = (unsigned)__builtin_amdgcn_update_dpp((int)_hi, (int)_hi, CTRL,    \
                                                          0xF, 0xF, false);            \
    unsigned long long _ok = (((unsigned long long)_phi) << 32) | _plo;                \
    if (_ok < (k)) (k) = _ok;                                                          \
  } while (0)

// Exact-match squared distance for ballq: ((dx*dx + dy*dy) + dz*dz), rn ops, no FMA.
__device__ __forceinline__ float sqdist_rn(float px, float py, float pz,
                                           float qx, float qy, float qz) {
  float dx = px - qx, dy = py - qy, dz = pz - qz;
  return __fadd_rn(__fadd_rn(__fmul_rn(dx, dx), __fmul_rn(dy, dy)), __fmul_rn(dz, dz));
}

// ---------------------------------------------------------------------------
// Kernel 1: farthest point sampling. One block per batch, 512 threads, 16
// points/thread (8 f32x2 pairs) in registers; all coords mirrored in LDS
// (interleaved xyz, stride 12B) for low-latency winner-coord fetch. Per step:
//   update (packed math, no index tracking) -> wave VALUE max (6 cheap DPP
//   rounds) -> readlane(63) -> descending rescan for == wmax (exact min-index
//   tie-break) -> wave u32 index-min (6 cheap DPP rounds) -> lane63 writes
//   u64 key (~bits(wmax)<<32 | idx) to LDS -> ONE barrier -> 3 u64 DPP
//   rounds cross-wave -> winner coords via 3 broadcast ds_reads.
// Exact semantics: min over keys == argmax by (dist desc, index asc) ==
// jnp.argmax first-occurrence; p + (-q) == p - q bitwise; no FMA contraction.
// ---------------------------------------------------------------------------
__global__ __launch_bounds__(512) void fps_kernel(const float* __restrict__ xyz,
                                                  float* __restrict__ out_newxyz) {
  __shared__ float cds[NPTS * 3];  // interleaved [n] = {x,y,z}, addr stride 12B
  __shared__ unsigned long long wkeys[2][8];

  const int b = blockIdx.x;
  const int tid = threadIdx.x;
  const int lane = tid & 63;
  const int wv = tid >> 6;
  const float* xb = xyz + (size_t)b * 3 * NPTS;

  f32x2 X2[8], Y2[8], Z2[8], D2[8];
#pragma unroll
  for (int j = 0; j < 8; j++) {
    int n0 = tid + (2 * j) * 512, n1 = tid + (2 * j + 1) * 512;
    X2[j].x = xb[n0];            X2[j].y = xb[n1];
    Y2[j].x = xb[NPTS + n0];     Y2[j].y = xb[NPTS + n1];
    Z2[j].x = xb[2 * NPTS + n0]; Z2[j].y = xb[2 * NPTS + n1];
    D2[j].x = 1e10f;             D2[j].y = 1e10f;
    cds[n0 * 3 + 0] = X2[j].x; cds[n0 * 3 + 1] = Y2[j].x; cds[n0 * 3 + 2] = Z2[j].x;
    cds[n1 * 3 + 0] = X2[j].y; cds[n1 * 3 + 1] = Y2[j].y; cds[n1 * 3 + 2] = Z2[j].y;
  }
  __syncthreads();

  // selection 0 = point 0
  float sx = cds[0], sy = cds[1], sz = cds[2];
  unsigned c0i = 0, c1i = 0;  // per-thread stash of selection indices

  for (int t = 0; t < NSAMP; t++) {
    f32x2 nqx, nqy, nqz;
    nqx.x = -sx; nqx.y = -sx;
    nqy.x = -sy; nqy.y = -sy;
    nqz.x = -sz; nqz.y = -sz;

    // ---- distance update (no index tracking) ----
    float bvx = -1.0f, bvy = -1.0f;
#pragma unroll
    for (int j = 0; j < 8; j++) {
      f32x2 dx = pk_add(X2[j], nqx);
      f32x2 dy = pk_add(Y2[j], nqy);
      f32x2 dz = pk_add(Z2[j], nqz);
      f32x2 dd = pk_add(pk_add(pk_mul(dx, dx), pk_mul(dy, dy)), pk_mul(dz, dz));
      float m0 = fminf(D2[j].x, dd.x);
      float m1 = fminf(D2[j].y, dd.y);
      D2[j].x = m0;
      D2[j].y = m1;
      bvx = fmaxf(bvx, m0);
      bvy = fmaxf(bvy, m1);
    }
    float bv = fmaxf(bvx, bvy);

    // ---- wave value-max: 6 cheap DPP rounds, result in lane 63 ----
    DPP_FMAX_ROUND(bv, 0x111);
    DPP_FMAX_ROUND(bv, 0x112);
    DPP_FMAX_ROUND(bv, 0x114);
    DPP_FMAX_ROUND(bv, 0x118);
    DPP_FMAX_ROUND(bv, 0x142);
    DPP_FMAX_ROUND(bv, 0x143);
    float wval = __int_as_float(__builtin_amdgcn_readlane(__float_as_int(bv), 63));

    // ---- rescan (descending) for == wval: exact smallest-index tie-break ----
    int bj = 16;  // sentinel -> n >= 8192, can never beat a real index
#pragma unroll
    for (int j = 7; j >= 0; j--) {
      if (D2[j].y == wval) bj = 2 * j + 1;
      if (D2[j].x == wval) bj = 2 * j;
    }
    unsigned n = (unsigned)tid + ((unsigned)bj << 9);

    // ---- wave index-min: 6 cheap DPP rounds, result in lane 63 ----
    DPP_UMIN_ROUND(n, 0x111);
    DPP_UMIN_ROUND(n, 0x112);
    DPP_UMIN_ROUND(n, 0x114);
    DPP_UMIN_ROUND(n, 0x118);
    DPP_UMIN_ROUND(n, 0x142);
    DPP_UMIN_ROUND(n, 0x143);

    // ---- one LDS round-trip + 3 u64 rounds across the 8 wave winners ----
    unsigned long long key =
        (((unsigned long long)(~__float_as_uint(wval))) << 32) | (unsigned long long)n;
    const int par = t & 1;
    if (lane == 63) wkeys[par][wv] = key;
    __syncthreads();
    unsigned long long k8 = wkeys[par][lane & 7];
    DPP_MIN_ROUND(k8, 0xB1);   // quad_perm ^1
    DPP_MIN_ROUND(k8, 0x4E);   // quad_perm ^2
    DPP_MIN_ROUND(k8, 0x141);  // row_half_mirror
    unsigned wid = (unsigned)__builtin_amdgcn_readfirstlane((int)(unsigned)k8);

    // stash: selection (t+1) = wid  (selection 0 preset above)
    if (t + 1 == tid) c0i = wid;
    if (t + 1 == tid + 512) c1i = wid;

    // winner coords from LDS (uniform addr -> broadcast, ~130 cyc)
    sx = cds[wid * 3 + 0];
    sy = cds[wid * 3 + 1];
    sz = cds[wid * 3 + 2];
  }

  // epilogue: thread tid writes new_xyz columns tid and tid+512
  {
    float ax = cds[c0i * 3 + 0], ay = cds[c0i * 3 + 1], az = cds[c0i * 3 + 2];
    float bx = cds[c1i * 3 + 0], by = cds[c1i * 3 + 1], bz = cds[c1i * 3 + 2];
    out_newxyz[(b * 3 + 0) * NSAMP + tid] = ax;
    out_newxyz[(b * 3 + 1) * NSAMP + tid] = ay;
    out_newxyz[(b * 3 + 2) * NSAMP + tid] = az;
    out_newxyz[(b * 3 + 0) * NSAMP + 512 + tid] = bx;
    out_newxyz[(b * 3 + 1) * NSAMP + 512 + tid] = by;
    out_newxyz[(b * 3 + 2) * NSAMP + 512 + tid] = bz;
  }
}

// ---------------------------------------------------------------------------
// Kernel 2: ball query + attention mean. One wave per (b,s). Scans points in
// ascending index order in chunks of 64, collects the first K in-radius
// indices (ballot + prefix popcount), pads with the first hit.
// ---------------------------------------------------------------------------
__global__ __launch_bounds__(256) void ballq_kernel(const float* __restrict__ xyz,
                                                    const float* __restrict__ att,
                                                    const float* __restrict__ newxyz,
                                                    int* __restrict__ idx_out,
                                                    float* __restrict__ att_out) {
  __shared__ int rowbuf[4][KNB];
  const int wv = threadIdx.x >> 6;
  const int lane = threadIdx.x & 63;
  const int g = blockIdx.x * 4 + wv;  // b*NSAMP + s
  const int b = g >> 10;
  const int s = g & 1023;
  const float* xb = xyz + (size_t)b * 3 * NPTS;

  float qx = newxyz[(b * 3 + 0) * NSAMP + s];
  float qy = newxyz[(b * 3 + 1) * NSAMP + s];
  float qz = newxyz[(b * 3 + 2) * NSAMP + s];

  int have = 0;
  int firstn = 0;
  for (int c = 0; c < NPTS / 64; c++) {
    int n = c * 64 + lane;
    float dd = sqdist_rn(xb[n], xb[NPTS + n], xb[2 * NPTS + n], qx, qy, qz);
    bool inb = (dd <= 0.04f);
    unsigned long long m = __ballot(inb);
    if (have == 0 && m != 0ull) firstn = c * 64 + __builtin_ctzll(m);
    int pre = __popcll(m & ((1ull << lane) - 1ull));
    if (inb && (have + pre) < KNB) rowbuf[wv][have + pre] = n;
    have += __popcll(m);
    if (have >= KNB) break;
  }
  if (have > KNB) have = KNB;
  if (lane < KNB && lane >= have) rowbuf[wv][lane] = firstn;  // pad

  float av = 0.0f;
  if (lane < KNB) {
    int myidx = rowbuf[wv][lane];
    idx_out[(size_t)g * KNB + lane] = myidx;
    av = att[(size_t)b * NPTS + myidx];
  }
#pragma unroll
  for (int m = 1; m < 64; m <<= 1) av += __shfl_xor(av, m, 64);
  if (lane == 0) att_out[g] = av * 0.03125f;  // mean over K=32 (exact /32)
}

// ---------------------------------------------------------------------------
// Kernel 3: gather features + 3-layer MLP + max over K. One 256-thread block
// per (b,s). feat [67][32] and h [64][36] (padded stride) in LDS; weights
// streamed from global (L1/L2 broadcast). f32 fmaf throughout.
// ---------------------------------------------------------------------------
__global__ __launch_bounds__(256) void mlp_kernel(
    const float* __restrict__ xyz, const float* __restrict__ pts,
    const float* __restrict__ newxyz, const int* __restrict__ idx,
    const float* __restrict__ w0, const float* __restrict__ b0,
    const float* __restrict__ w1, const float* __restrict__ b1,
    const float* __restrict__ w2, const float* __restrict__ b2,
    float* __restrict__ out_np) {
  const int g = blockIdx.x;
  const int b = g >> 10;
  const int s = g & 1023;
  const int t = threadIdx.x;

  __shared__ __align__(16) float feat[67 * 32];
  __shared__ __align__(16) float h0s[64 * 36];
  __shared__ __align__(16) float h1s[64 * 36];
  __shared__ int sidx[KNB];

  if (t < KNB) sidx[t] = idx[(size_t)g * KNB + t];
  __syncthreads();

  // gather: rows 0..2 = g_norm (xyz - query), rows 3..66 = point features
  {
    int k = t & 31, rg = t >> 5;
    int n = sidx[k];
    const float* pb = pts + (size_t)b * 64 * NPTS;
    for (int r = rg; r < 67; r += 8) {
      float v;
      if (r < 3)
        v = xyz[((size_t)b * 3 + r) * NPTS + n] - newxyz[(b * 3 + r) * NSAMP + s];
      else
        v = pb[(size_t)(r - 3) * NPTS + n];
      feat[r * 32 + k] = v;
    }
  }
  __syncthreads();

  const int kq = t & 7;   // k block = 4*kq .. +4
  const int og = t >> 3;  // o = 2*og, 2*og+1

  // ---- layer 0: 67 -> 64 ----
  {
    float a0[8];
    float bu = b0[2 * og], bw = b0[2 * og + 1];
    a0[0] = a0[1] = a0[2] = a0[3] = bu;
    a0[4] = a0[5] = a0[6] = a0[7] = bw;
    const float* wr0 = w0 + (2 * og) * 67;
    const float* wr1 = wr0 + 67;
    for (int c = 0; c < 67; c++) {
      float4 f = *(const float4*)&feat[c * 32 + kq * 4];
      float u = wr0[c], v = wr1[c];
      a0[0] = fmaf(u, f.x, a0[0]); a0[1] = fmaf(u, f.y, a0[1]);
      a0[2] = fmaf(u, f.z, a0[2]); a0[3] = fmaf(u, f.w, a0[3]);
      a0[4] = fmaf(v, f.x, a0[4]); a0[5] = fmaf(v, f.y, a0[5]);
      a0[6] = fmaf(v, f.z, a0[6]); a0[7] = fmaf(v, f.w, a0[7]);
    }
    float4 r0, r1;
    r0.x = fmaxf(a0[0], 0.f); r0.y = fmaxf(a0[1], 0.f);
    r0.z = fmaxf(a0[2], 0.f); r0.w = fmaxf(a0[3], 0.f);
    r1.x = fmaxf(a0[4], 0.f); r1.y = fmaxf(a0[5], 0.f);
    r1.z = fmaxf(a0[6], 0.f); r1.w = fmaxf(a0[7], 0.f);
    *(float4*)&h0s[(2 * og) * 36 + kq * 4] = r0;
    *(float4*)&h0s[(2 * og + 1) * 36 + kq * 4] = r1;
  }
  __syncthreads();

  // ---- layer 1: 64 -> 64 ----
  {
    float a1[8];
    float bu = b1[2 * og], bw = b1[2 * og + 1];
    a1[0] = a1[1] = a1[2] = a1[3] = bu;
    a1[4] = a1[5] = a1[6] = a1[7] = bw;
    const float* wr0 = w1 + (2 * og) * 64;
    const float* wr1 = wr0 + 64;
    for (int c = 0; c < 64; c++) {
      float4 f = *(const float4*)&h0s[c * 36 + kq * 4];
      float u = wr0[c], v = wr1[c];
      a1[0] = fmaf(u, f.x, a1[0]); a1[1] = fmaf(u, f.y, a1[1]);
      a1[2] = fmaf(u, f.z, a1[2]); a1[3] = fmaf(u, f.w, a1[3]);
      a1[4] = fmaf(v, f.x, a1[4]); a1[5] = fmaf(v, f.y, a1[5]);
      a1[6] = fmaf(v, f.z, a1[6]); a1[7] = fmaf(v, f.w, a1[7]);
    }
    float4 r0, r1;
    r0.x = fmaxf(a1[0], 0.f); r0.y = fmaxf(a1[1], 0.f);
    r0.z = fmaxf(a1[2], 0.f); r0.w = fmaxf(a1[3], 0.f);
    r1.x = fmaxf(a1[4], 0.f); r1.y = fmaxf(a1[5], 0.f);
    r1.z = fmaxf(a1[6], 0.f); r1.w = fmaxf(a1[7], 0.f);
    *(float4*)&h1s[(2 * og) * 36 + kq * 4] = r0;
    *(float4*)&h1s[(2 * og + 1) * 36 + kq * 4] = r1;
  }
  __syncthreads();

  // ---- layer 2: 64 -> 128, then max over k ----
  {
    const int kq2 = t & 3;   // k block = 8*kq2 .. +8
    const int og2 = t >> 2;  // o = 2*og2, 2*og2+1
    float a2[16];
    float bu = b2[2 * og2], bw = b2[2 * og2 + 1];
#pragma unroll
    for (int i = 0; i < 8; i++) { a2[i] = bu; a2[8 + i] = bw; }
    const float* wr0 = w2 + (2 * og2) * 64;
    const float* wr1 = wr0 + 64;
    for (int c = 0; c < 64; c++) {
      float4 fA = *(const float4*)&h1s[c * 36 + kq2 * 8];
      float4 fB = *(const float4*)&h1s[c * 36 + kq2 * 8 + 4];
      float u = wr0[c], v = wr1[c];
      a2[0] = fmaf(u, fA.x, a2[0]);  a2[1] = fmaf(u, fA.y, a2[1]);
      a2[2] = fmaf(u, fA.z, a2[2]);  a2[3] = fmaf(u, fA.w, a2[3]);
      a2[4] = fmaf(u, fB.x, a2[4]);  a2[5] = fmaf(u, fB.y, a2[5]);
      a2[6] = fmaf(u, fB.z, a2[6]);  a2[7] = fmaf(u, fB.w, a2[7]);
      a2[8] = fmaf(v, fA.x, a2[8]);  a2[9] = fmaf(v, fA.y, a2[9]);
      a2[10] = fmaf(v, fA.z, a2[10]); a2[11] = fmaf(v, fA.w, a2[11]);
      a2[12] = fmaf(v, fB.x, a2[12]); a2[13] = fmaf(v, fB.y, a2[13]);
      a2[14] = fmaf(v, fB.z, a2[14]); a2[15] = fmaf(v, fB.w, a2[15]);
    }
    // relu then max over k == max then relu (relu is monotone)
    float m0 = a2[0], m1 = a2[8];
#pragma unroll
    for (int i = 1; i < 8; i++) { m0 = fmaxf(m0, a2[i]); m1 = fmaxf(m1, a2[8 + i]); }
    m0 = fmaxf(m0, 0.f);
    m1 = fmaxf(m1, 0.f);
    // reduce over the 4 lanes sharing og2 (kq2 = 0..3, adjacent lanes)
    m0 = fmaxf(m0, __shfl_xor(m0, 1, 64));
    m0 = fmaxf(m0, __shfl_xor(m0, 2, 64));
    m1 = fmaxf(m1, __shfl_xor(m1, 1, 64));
    m1 = fmaxf(m1, __shfl_xor(m1, 2, 64));
    if (kq2 == 0) {
      out_np[((size_t)b * 128 + 2 * og2) * NSAMP + s] = m0;
      out_np[((size_t)b * 128 + 2 * og2 + 1) * NSAMP + s] = m1;
    }
  }
}

extern "C" void kernel_launch(void* const* d_in, const int* in_sizes, int n_in,
                              void* d_out, int out_size, void* d_ws, size_t ws_size,
                              hipStream_t stream) {
  (void)in_sizes; (void)n_in; (void)out_size; (void)ws_size;
  const float* xyz = (const float*)d_in[0];
  const float* pts = (const float*)d_in[1];
  const float* att = (const float*)d_in[2];
  const float* w0 = (const float*)d_in[3];
  const float* b0 = (const float*)d_in[4];
  const float* w1 = (const float*)d_in[5];
  const float* b1 = (const float*)d_in[6];
  const float* w2 = (const float*)d_in[7];
  const float* b2 = (const float*)d_in[8];

  float* out = (float*)d_out;
  float* out_newxyz = out;                                     // (B,3,S)
  float* out_newpts = out + NBATCH * 3 * NSAMP;                // (B,128,S)
  float* out_att = out + NBATCH * 3 * NSAMP + NBATCH * 128 * NSAMP;  // (B,1,S)
  int* idx_ws = (int*)d_ws;  // (B*S, K) int32 = 1 MB

  fps_kernel<<<NBATCH, 512, 0, stream>>>(xyz, out_newxyz);
  ballq_kernel<<<(NBATCH * NSAMP) / 4, 256, 0, stream>>>(xyz, att, out_newxyz, idx_ws, out_att);
  mlp_kernel<<<NBATCH * NSAMP, 256, 0, stream>>>(xyz, pts, out_newxyz, idx_ws,
                                                 w0, b0, w1, b1, w2, b2, out_newpts);
}